// Round 11
// baseline (117.550 us; speedup 1.0000x reference)
//
#include <hip/hip_runtime.h>
#include <math.h>

// VectorQuantizer on MI355X — R11: prep-packed W + global_load_lds staging
// + 4-sub B-reuse. R10 got total to 116.7 µs; top-5 is now all harness d_ws
// re-poison fills (~42 µs, fixed). Controllable remainder: main ~35-40 µs.
// R11 removes main's per-block W conversion (vq_prep packs bf16-frag W + wsqp
// into ws once; staging = 16 global_load_lds width-16 instrs, zero VALU) and
// halves scan ds_read_b128 via 64 tokens/wave (4 subs per B-frag pair).
// No global atomics (R9's win), no memset (everything fully overwritten).
// ws: [0,64K) wpack bf16-frag | [64K,+2K) wsqp | [66K,+1M) pcounts[512][512]
//     | then ssep f64[512]

#define NTOK 131072
#define KCODES 512
#define HW 4096
#define CHW 262144
#define NELEM 8388608

typedef __attribute__((ext_vector_type(8))) short short8;
typedef __attribute__((ext_vector_type(4))) float f32x4;

static __device__ __forceinline__ unsigned short f2bf(float f) {
    unsigned u = __float_as_uint(f);
    unsigned r = u + 0x7FFFu + ((u >> 16) & 1u);  // RNE
    return (unsigned short)(r >> 16);
}

static __device__ __forceinline__ void gload16_lds(const void* g, void* l) {
    __builtin_amdgcn_global_load_lds(
        (const __attribute__((address_space(1))) void*)g,
        (__attribute__((address_space(3))) void*)l, 16, 0, 0);
}

// blocks 0-7: pack W into frag-layout bf16; block 8: wsqp = 1.25 + ||w_k||^2
__global__ __launch_bounds__(512) void vq_prep(const float* __restrict__ w,
                                               unsigned short* __restrict__ wpack,
                                               float* __restrict__ wsqp) {
    const int tid = threadIdx.x;
    if (blockIdx.x < 8) {
        const int g = blockIdx.x * 512 + tid;  // [0,4096) 16B chunks
        const int cc = g & 15, qd = (g >> 4) & 3, ch = (g >> 6) & 1, tt = g >> 7;
        const float4* src = (const float4*)(w + (tt * 16 + cc) * 64 + ch * 32 + qd * 8);
        const float4 v0 = src[0], v1 = src[1];
        short8 hv;
        hv[0] = (short)f2bf(v0.x); hv[1] = (short)f2bf(v0.y);
        hv[2] = (short)f2bf(v0.z); hv[3] = (short)f2bf(v0.w);
        hv[4] = (short)f2bf(v1.x); hv[5] = (short)f2bf(v1.y);
        hv[6] = (short)f2bf(v1.z); hv[7] = (short)f2bf(v1.w);
        *(short8*)(wpack + g * 8) = hv;
    } else {
        const float* wr = w + (tid << 6);
        float s = 0.f;
#pragma unroll
        for (int i = 0; i < 64; ++i) s = fmaf(wr[i], wr[i], s);
        wsqp[tid] = 1.25f + s;
    }
}

__global__ __launch_bounds__(256, 2) void vq_main(const float* __restrict__ in,
                                                  const float* __restrict__ w,
                                                  const unsigned short* __restrict__ wpack,
                                                  const float* __restrict__ wsqp_g,
                                                  float* __restrict__ out,
                                                  float* __restrict__ pcounts,
                                                  double* __restrict__ ssep) {
    __shared__ unsigned short wh[KCODES * 64];  // 65536 B, frag-packed bf16 W
    __shared__ float wsqp[KCODES];              // 2048 B
    __shared__ int idxbuf[256];                 // 1024 B
    __shared__ int hist[KCODES];                // 2048 B
    __shared__ double sred[4];

    const int tid = threadIdx.x;
    const int lane = tid & 63, wv = tid >> 6;   // 4 waves
    const int col = lane & 15, quad = lane >> 4;
    const int ntok0 = blockIdx.x * 256;

    hist[tid] = 0;
    hist[tid + 256] = 0;
    wsqp[tid] = wsqp_g[tid];
    wsqp[tid + 256] = wsqp_g[tid + 256];

    // ---- staging: 16 global_load_lds (16B/lane, lane-contiguous both sides) ----
#pragma unroll
    for (int it = 0; it < 16; ++it) {
        const int g = it * 256 + tid;
        gload16_lds(wpack + g * 8, wh + (it * 256 + wv * 64) * 8);
    }

    // ---- gather: 64 tokens/wave, 64 dims; 4 full 64B lines per instr ----
    const float* gbase = in + (ntok0 >> 12) * CHW + (ntok0 & 4095) + wv * 64 + col;
    short8 ah[4][2];
    float xsq = 0.f;
#pragma unroll
    for (int sub = 0; sub < 4; ++sub) {
        const float* bp = gbase + sub * 16;
#pragma unroll
        for (int c = 0; c < 2; ++c)
#pragma unroll
            for (int j = 0; j < 8; ++j) {
                const float x = bp[(c * 32 + quad * 8 + j) * HW];
                xsq = fmaf(x, x, xsq);
                ah[sub][c][j] = (short)f2bf(-2.0f * x);
            }
    }
    __syncthreads();  // B2: wh (vmcnt drained) + wsqp + hist init

    // ---- scan 32 tiles of 16 codes; key = (float_bits(d)<<9)|code ----
    unsigned runkey[4][4];
#pragma unroll
    for (int sub = 0; sub < 4; ++sub)
#pragma unroll
        for (int r = 0; r < 4; ++r) runkey[sub][r] = 0xFFFFFFFFu;

#pragma unroll 1
    for (int t = 0; t < 32; ++t) {
        const unsigned short* ph = wh + t * 1024 + quad * 128 + col * 8;
        const short8 b0 = *(const short8*)ph;
        const short8 b1 = *(const short8*)(ph + 512);
        const int code = t * 16 + col;
        const float seed = wsqp[code];
#pragma unroll
        for (int sub = 0; sub < 4; ++sub) {
            f32x4 acc = {seed, seed, seed, seed};
            acc = __builtin_amdgcn_mfma_f32_16x16x32_bf16(ah[sub][0], b0, acc, 0, 0, 0);
            acc = __builtin_amdgcn_mfma_f32_16x16x32_bf16(ah[sub][1], b1, acc, 0, 0, 0);
#pragma unroll
            for (int r = 0; r < 4; ++r) {
                const unsigned key = (__float_as_uint(acc[r]) << 9) | code;
                runkey[sub][r] = key < runkey[sub][r] ? key : runkey[sub][r];
            }
        }
    }

    // ---- cross-lane argmin over the 16 code-cols ----
#pragma unroll
    for (int s = 1; s < 16; s <<= 1)
#pragma unroll
        for (int sub = 0; sub < 4; ++sub)
#pragma unroll
            for (int r = 0; r < 4; ++r) {
                const unsigned o = __shfl_xor(runkey[sub][r], s, 64);
                runkey[sub][r] = o < runkey[sub][r] ? o : runkey[sub][r];
            }

    float dsum = 0.f;
    if (col == 0) {
#pragma unroll
        for (int sub = 0; sub < 4; ++sub)
#pragma unroll
            for (int r = 0; r < 4; ++r) {
                const unsigned key = runkey[sub][r];
                idxbuf[wv * 64 + sub * 16 + quad * 4 + r] = (int)(key & 511u);
                dsum += __uint_as_float((key >> 9) | 0x3F800000u) - 1.25f;
            }
    }
    float contrib = xsq + dsum;
#pragma unroll
    for (int off = 32; off > 0; off >>= 1) contrib += __shfl_down(contrib, off, 64);
    if (lane == 0) sred[wv] = (double)contrib;
    __syncthreads();  // B3: idxbuf + sred visible

    atomicAdd(&hist[idxbuf[tid]], 1);  // LDS histogram, 256 tokens

    // ---- epilogue: write w rows (L2-hot); 4 lanes/token, 4 passes ----
#pragma unroll
    for (int p = 0; p < 4; ++p) {
        const int tl = p * 16 + (lane >> 2), q = lane & 3;
        const int n = ntok0 + wv * 64 + tl;
        const int bidx = idxbuf[wv * 64 + tl];
        const float4* wr = (const float4*)(w + bidx * 64 + q * 16);
        float4* op = (float4*)(out + n * 64 + q * 16);
#pragma unroll
        for (int i = 0; i < 4; ++i) op[i] = wr[i];
    }
    __syncthreads();  // B4: hist complete

    pcounts[(blockIdx.x << 9) + tid] = (float)hist[tid];
    pcounts[(blockIdx.x << 9) + tid + 256] = (float)hist[tid + 256];
    if (tid == 0)
        ssep[blockIdx.x] = (sred[0] + sred[1]) + (sred[2] + sred[3]);
}

// parallel reduce: thread t owns 4 codes x 1 block-quarter; float4 coalesced
__global__ __launch_bounds__(512) void vq_final_p(const float* __restrict__ pcounts,
                                                  const double* __restrict__ ssep,
                                                  float* __restrict__ out) {
    __shared__ float part[4][512];
    __shared__ double red[512];
    __shared__ double sred[512];
    const int t = threadIdx.x;
    const int q = t >> 7, c4 = (t & 127) << 2;

    const float4* base = (const float4*)pcounts + (q << 14) + (c4 >> 2);
    float4 s = {0.f, 0.f, 0.f, 0.f};
#pragma unroll 16
    for (int b = 0; b < 128; ++b) {
        const float4 v = base[b << 7];
        s.x += v.x; s.y += v.y; s.z += v.z; s.w += v.w;
    }
    *(float4*)&part[q][c4] = s;
    sred[t] = ssep[t];
    __syncthreads();

    const float cnt = part[0][t] + part[1][t] + part[2][t] + part[3][t];
    const double p = (double)cnt / (double)NTOK;
    red[t] = p * log(p + 1e-10);
    __syncthreads();
#pragma unroll
    for (int st = 256; st > 0; st >>= 1) {
        if (t < st) { red[t] += red[t + st]; sred[t] += sred[t + st]; }
        __syncthreads();
    }
    if (t == 0) {
        out[NELEM] = (float)((sred[0] / (double)NELEM) * 1.25);
        out[NELEM + 1] = (float)exp(-red[0]);
    }
}

extern "C" void kernel_launch(void* const* d_in, const int* in_sizes, int n_in,
                              void* d_out, int out_size, void* d_ws, size_t ws_size,
                              hipStream_t stream) {
    const float* in = (const float*)d_in[0];
    const float* w = (const float*)d_in[1];
    float* out = (float*)d_out;
    char* ws = (char*)d_ws;

    unsigned short* wpack = (unsigned short*)ws;            // 65536 B
    float* wsqp = (float*)(ws + 65536);                     // 2048 B
    float* pcounts = (float*)(ws + 67584);                  // 1 MB
    double* ssep = (double*)(ws + 67584 + (size_t)1048576); // 4 KB

    vq_prep<<<9, 512, 0, stream>>>(w, wpack, wsqp);
    vq_main<<<512, 256, 0, stream>>>(in, w, wpack, wsqp, out, pcounts, ssep);
    vq_final_p<<<1, 512, 0, stream>>>(pcounts, ssep, out);
}